// Round 4
// baseline (444.496 us; speedup 1.0000x reference)
//
#include <hip/hip_runtime.h>

// BiDAF-style fused kernel for B=32, L=D=768, fp32.
//
// Algebraic collapse:
//   w3hq[b,i] = h[b,i,:] . v[b,:],  v[b,d] = sum_m q[b,m,d]*w3_w[m]   (no L*L bmm)
//   p[b,i,j]  = softmax_j(w2q[b,:])[j] = s2[b,j]      (row-constant cancels exactly)
//   p2[b,i]   = softmax_i(w1h[b,i]+w3hq[b,i])         (col-constant cancels exactly)
//   out = [h, q*s2, h*q*s2, h*p2*q*s2] along axis 1.

#define NB 32
#define NL 768
#define ND 768
#define ND4 (ND/4)     // 192
#define CH 32          // row-chunks per batch for phase1/phase2
#define RPB (NL/CH)    // 24 rows per block

// clang native vector type for nontemporal builtins (HIP float4 is a class).
typedef float vf4 __attribute__((ext_vector_type(4)));

__device__ __forceinline__ float dot4(float4 a, float4 b) {
    return a.x*b.x + a.y*b.y + a.z*b.z + a.w*b.w;
}
__device__ __forceinline__ float4 f4mul(float4 a, float4 b) {
    return make_float4(a.x*b.x, a.y*b.y, a.z*b.z, a.w*b.w);
}
__device__ __forceinline__ float4 f4muls(float4 a, float s) {
    return make_float4(a.x*s, a.y*s, a.z*s, a.w*s);
}
__device__ __forceinline__ float4 f4fmas(float4 a, float s, float4 c) {
    return make_float4(fmaf(a.x,s,c.x), fmaf(a.y,s,c.y), fmaf(a.z,s,c.z), fmaf(a.w,s,c.w));
}
__device__ __forceinline__ float4 fromv(vf4 v) {
    return make_float4(v.x, v.y, v.z, v.w);
}
__device__ __forceinline__ vf4 tov(float4 v) {
    vf4 r; r.x = v.x; r.y = v.y; r.z = v.z; r.w = v.w; return r;
}

__global__ void k_zero(float* __restrict__ p, int n) {
    int i = blockIdx.x * blockDim.x + threadIdx.x;
    if (i < n) p[i] = 0.0f;
}

// One pass over h and q: per-row dots (w1h, w2q) + column-weighted reduce of q into v.
// grid (CH, NB), block 256 (4 waves). Wave-per-row; lane owns cols {4l..4l+3, +256, +512}.
__global__ __launch_bounds__(256) void k_phase1(
    const float* __restrict__ h, const float* __restrict__ q,
    const float* __restrict__ w1_w, const float* __restrict__ w1_b,
    const float* __restrict__ w2_w, const float* __restrict__ w2_b,
    const float* __restrict__ w3_w,
    float* __restrict__ w1h, float* __restrict__ w2q, float* __restrict__ v)
{
    __shared__ float vsh[4][ND];
    const int b    = blockIdx.y;
    const int ch   = blockIdx.x;
    const int tid  = threadIdx.x;
    const int wave = tid >> 6;
    const int lane = tid & 63;

    const float4* w1w4 = (const float4*)w1_w;
    const float4* w2w4 = (const float4*)w2_w;
    const float4 a0 = w1w4[lane], a1 = w1w4[lane+64], a2 = w1w4[lane+128];
    const float4 c0 = w2w4[lane], c1 = w2w4[lane+64], c2 = w2w4[lane+128];
    const float b1 = w1_b[0], b2 = w2_b[0];

    float4 v0 = make_float4(0,0,0,0);
    float4 v1 = make_float4(0,0,0,0);
    float4 v2 = make_float4(0,0,0,0);

    const int row0 = ch * RPB;
    #pragma unroll
    for (int k = 0; k < RPB/4; ++k) {
        const int row = row0 + wave + 4*k;
        const float4* hr = (const float4*)(h + ((size_t)b*NL + row)*ND);
        const float4* qr = (const float4*)(q + ((size_t)b*NL + row)*ND);
        float4 h0 = hr[lane], h1 = hr[lane+64], h2 = hr[lane+128];
        float4 q0 = qr[lane], q1 = qr[lane+64], q2 = qr[lane+128];
        float d1 = dot4(h0,a0) + dot4(h1,a1) + dot4(h2,a2);
        float d2 = dot4(q0,c0) + dot4(q1,c1) + dot4(q2,c2);
        const float w3r = w3_w[row];
        v0 = f4fmas(q0, w3r, v0);
        v1 = f4fmas(q1, w3r, v1);
        v2 = f4fmas(q2, w3r, v2);
        #pragma unroll
        for (int off = 32; off; off >>= 1) {
            d1 += __shfl_xor(d1, off);
            d2 += __shfl_xor(d2, off);
        }
        if (lane == 0) {
            w1h[b*NL + row] = d1 + b1;
            w2q[b*NL + row] = d2 + b2;
        }
    }
    // combine per-wave v partials, then one atomicAdd per column per block
    *(float4*)&vsh[wave][4*lane]       = v0;
    *(float4*)&vsh[wave][256 + 4*lane] = v1;
    *(float4*)&vsh[wave][512 + 4*lane] = v2;
    __syncthreads();
    for (int c = tid; c < ND; c += 256) {
        float s = vsh[0][c] + vsh[1][c] + vsh[2][c] + vsh[3][c];
        atomicAdd(&v[b*ND + c], s);
    }
}

// r[b,i] = w1h[b,i] + h[b,i,:].v[b,:] + w3_b.  grid (CH, NB), block 256.
__global__ __launch_bounds__(256) void k_phase2(
    const float* __restrict__ h, const float* __restrict__ v,
    const float* __restrict__ w3_b, const float* __restrict__ w1h,
    float* __restrict__ r)
{
    const int b    = blockIdx.y;
    const int ch   = blockIdx.x;
    const int tid  = threadIdx.x;
    const int wave = tid >> 6;
    const int lane = tid & 63;

    const float4* vb = (const float4*)(v + (size_t)b*ND);
    const float4 v0 = vb[lane], v1 = vb[lane+64], v2 = vb[lane+128];
    const float b3 = w3_b[0];

    const int row0 = ch * RPB;
    #pragma unroll
    for (int k = 0; k < RPB/4; ++k) {
        const int row = row0 + wave + 4*k;
        const float4* hr = (const float4*)(h + ((size_t)b*NL + row)*ND);
        float4 h0 = hr[lane], h1 = hr[lane+64], h2 = hr[lane+128];
        float d = dot4(h0,v0) + dot4(h1,v1) + dot4(h2,v2);
        #pragma unroll
        for (int off = 32; off; off >>= 1) d += __shfl_xor(d, off);
        if (lane == 0) r[b*NL + row] = w1h[b*NL + row] + d + b3;
    }
}

// Per-batch softmaxes: s2 = softmax(w2q[b,:]), p2 = softmax(r[b,:]). grid (NB), block 256.
__global__ __launch_bounds__(256) void k_softmax(
    const float* __restrict__ w2q, const float* __restrict__ r,
    float* __restrict__ s2, float* __restrict__ p2)
{
    __shared__ float sm[256];
    const int b = blockIdx.x, t = threadIdx.x;
    const float* src = w2q;
    float* dst = s2;
    for (int pass = 0; pass < 2; ++pass) {
        float x0 = src[b*NL + t], x1 = src[b*NL + t + 256], x2 = src[b*NL + t + 512];
        float m = fmaxf(x0, fmaxf(x1, x2));
        sm[t] = m; __syncthreads();
        #pragma unroll
        for (int s = 128; s > 0; s >>= 1) {
            if (t < s) sm[t] = fmaxf(sm[t], sm[t+s]);
            __syncthreads();
        }
        m = sm[0]; __syncthreads();
        float e0 = expf(x0 - m), e1 = expf(x1 - m), e2 = expf(x2 - m);
        sm[t] = e0 + e1 + e2; __syncthreads();
        #pragma unroll
        for (int s = 128; s > 0; s >>= 1) {
            if (t < s) sm[t] += sm[t+s];
            __syncthreads();
        }
        float inv = 1.0f / sm[0]; __syncthreads();
        dst[b*NL + t]       = e0 * inv;
        dst[b*NL + t + 256] = e1 * inv;
        dst[b*NL + t + 512] = e2 * inv;
        src = r; dst = p2;
    }
}

// out[b] = concat([h, c, h*c, (h*p2)*c], axis=0 of sections), c = q*s2 (broadcast over rows).
// Non-temporal: h/q last use (nt load), out write-once (nt store).
__global__ __launch_bounds__(256) void k_out(
    const float* __restrict__ h, const float* __restrict__ q,
    const float* __restrict__ s2, const float* __restrict__ p2,
    float* __restrict__ out)
{
    const int NU = NB * NL * ND4;         // 4,718,592 float4 units per input tensor
    const size_t S = (size_t)NL * ND4;    // float4s per output section
    const vf4* h4  = (const vf4*)h;
    const vf4* q4  = (const vf4*)q;
    const float4* s24 = (const float4*)s2;
    vf4* o4 = (vf4*)out;
    for (int u = blockIdx.x * blockDim.x + threadIdx.x; u < NU;
         u += gridDim.x * blockDim.x) {
        const int d4  = u % ND4;
        const int rem = u / ND4;
        const int i   = rem % NL;
        const int b   = rem / NL;
        float4 hh = fromv(__builtin_nontemporal_load(&h4[u]));
        float4 qq = fromv(__builtin_nontemporal_load(&q4[u]));
        float4 ss = s24[b*ND4 + d4];
        float  pp = p2[b*NL + i];
        float4 cc = f4mul(qq, ss);
        size_t ob = (size_t)b*(4*S) + (size_t)i*ND4 + d4;
        __builtin_nontemporal_store(tov(hh), &o4[ob]);
        __builtin_nontemporal_store(tov(cc), &o4[ob + S]);
        __builtin_nontemporal_store(tov(f4mul(hh, cc)), &o4[ob + 2*S]);
        __builtin_nontemporal_store(tov(f4mul(f4muls(hh, pp), cc)), &o4[ob + 3*S]);
    }
}

extern "C" void kernel_launch(void* const* d_in, const int* in_sizes, int n_in,
                              void* d_out, int out_size, void* d_ws, size_t ws_size,
                              hipStream_t stream) {
    const float* h    = (const float*)d_in[0];
    const float* q    = (const float*)d_in[1];
    const float* w1_w = (const float*)d_in[2];
    const float* w1_b = (const float*)d_in[3];
    const float* w2_w = (const float*)d_in[4];
    const float* w2_b = (const float*)d_in[5];
    const float* w3_w = (const float*)d_in[6];
    const float* w3_b = (const float*)d_in[7];
    float* out = (float*)d_out;

    float* ws  = (float*)d_ws;
    float* w1h = ws;                 // B*L
    float* w2q = ws + 1*NB*NL;       // B*L
    float* r   = ws + 2*NB*NL;       // B*L
    float* s2  = ws + 3*NB*NL;       // B*L
    float* p2  = ws + 4*NB*NL;       // B*L
    float* v   = ws + 5*NB*NL;       // B*D   (total 589,824 B of ws)

    hipLaunchKernelGGL(k_zero, dim3((NB*ND + 255)/256), dim3(256), 0, stream,
                       v, NB*ND);
    hipLaunchKernelGGL(k_phase1, dim3(CH, NB), dim3(256), 0, stream,
                       h, q, w1_w, w1_b, w2_w, w2_b, w3_w, w1h, w2q, v);
    hipLaunchKernelGGL(k_phase2, dim3(CH, NB), dim3(256), 0, stream,
                       h, v, w3_b, w1h, r);
    hipLaunchKernelGGL(k_softmax, dim3(NB), dim3(256), 0, stream,
                       w2q, r, s2, p2);
    hipLaunchKernelGGL(k_out, dim3(2048), dim3(256), 0, stream,
                       h, q, s2, p2, out);
}